// Round 2
// baseline (400.429 us; speedup 1.0000x reference)
//
#include <hip/hip_runtime.h>

#define B_   4
#define C_   512
#define S_   4096
#define G_   32
#define CPG_ 16
#define EPS_ 1e-6f

typedef unsigned short u16;
typedef __bf16 bf16x8 __attribute__((ext_vector_type(8)));
typedef float  f32x4  __attribute__((ext_vector_type(4)));

__device__ __forceinline__ u16 f2bf(float f) {
  unsigned u = __float_as_uint(f);
  u += 0x7fffu + ((u >> 16) & 1u);   // RNE
  return (u16)(u >> 16);
}
__device__ __forceinline__ float bf2f(u16 h) {
  return __uint_as_float((unsigned)h << 16);
}

__device__ __forceinline__ void g2lds16(const void* g, void* l) {
  __builtin_amdgcn_global_load_lds(
      (const __attribute__((address_space(1))) void*)g,
      (__attribute__((address_space(3))) void*)l, 16, 0, 0);
}

#define BAR()    __builtin_amdgcn_s_barrier()
#define SCHED0() __builtin_amdgcn_sched_barrier(0)
#define WAITV8   asm volatile("s_waitcnt vmcnt(8)" ::: "memory")
#define WAITV4   asm volatile("s_waitcnt vmcnt(4)" ::: "memory")
#define WAITV0   asm volatile("s_waitcnt vmcnt(0)" ::: "memory")

// ---------------- fp32 -> bf16 weight conversion ----------------
__global__ __launch_bounds__(256) void f32_to_bf16(const float* __restrict__ in,
                                                   u16* __restrict__ out, int n) {
  int i = blockIdx.x * 256 + threadIdx.x;
  if (i < n) out[i] = f2bf(in[i]);
}

__global__ __launch_bounds__(256) void concat_bias(const float* __restrict__ a,
                                                   const float* __restrict__ b,
                                                   float* __restrict__ o) {
  int i = blockIdx.x * 256 + threadIdx.x;  // grid 4 -> 1024
  o[i] = (i < 512) ? a[i] : b[i - 512];
}

// ---------------- GroupNorm stats: one block per (b,g) ----------------
__global__ __launch_bounds__(256) void gn_stats(const float* __restrict__ x,
                                                float* __restrict__ stats) {
  const int bg = blockIdx.x;
  const float4* p4 = (const float4*)(x + (size_t)bg * (CPG_ * S_));
  float s = 0.f, ss = 0.f;
  const int tid = threadIdx.x;
  for (int i = tid; i < CPG_ * S_ / 4; i += 256) {
    float4 v = p4[i];
    s  += v.x + v.y + v.z + v.w;
    ss += v.x * v.x + v.y * v.y + v.z * v.z + v.w * v.w;
  }
#pragma unroll
  for (int o = 32; o; o >>= 1) { s += __shfl_xor(s, o, 64); ss += __shfl_xor(ss, o, 64); }
  __shared__ float sm[8];
  const int wid = tid >> 6, lane = tid & 63;
  if (lane == 0) { sm[wid * 2] = s; sm[wid * 2 + 1] = ss; }
  __syncthreads();
  if (tid == 0) {
    s  = sm[0] + sm[2] + sm[4] + sm[6];
    ss = sm[1] + sm[3] + sm[5] + sm[7];
    const float inv = 1.f / (float)(CPG_ * S_);
    float mu = s * inv;
    float var = ss * inv - mu * mu;
    stats[bg * 2]     = mu;
    stats[bg * 2 + 1] = rsqrtf(var + EPS_);
  }
}

// ---------------- normalize + transpose: x[b,c,s] -> ht[b*s, c] bf16 ----------------
__global__ __launch_bounds__(256) void gn_apply_t(const float* __restrict__ x,
                                                  const float* __restrict__ gamma,
                                                  const float* __restrict__ beta,
                                                  const float* __restrict__ stats,
                                                  u16* __restrict__ ht) {
  __shared__ float tile[32][33];
  const int b = blockIdx.z, c0 = blockIdx.y * 32, s0 = blockIdx.x * 32;
  const int tx = threadIdx.x, ty = threadIdx.y;
#pragma unroll
  for (int i = 0; i < 4; ++i) {
    const int c  = c0 + ty + i * 8;
    const float mu = stats[(b * G_ + (c >> 4)) * 2];
    const float rs = stats[(b * G_ + (c >> 4)) * 2 + 1];
    const float v  = x[((size_t)b * C_ + c) * S_ + s0 + tx];
    tile[ty + i * 8][tx] = (v - mu) * rs * gamma[c] + beta[c];
  }
  __syncthreads();
#pragma unroll
  for (int i = 0; i < 4; ++i) {
    const int s = s0 + ty + i * 8;
    ht[((size_t)b * S_ + s) * C_ + c0 + tx] = f2bf(tile[tx][ty + i * 8]);
  }
}

// ================= 256x256 phase-split GEMM (T2+T3+T4+T5) =================
// C[m,n] = alpha * sum_k A[m,k]*B[n,k] (+bias[n]); A,B bf16 K-contiguous.
// 512 thr = 8 waves (2m x 4n), per-wave 128x64 (8x4 frags of 16x16x32).
// LDS: per operand a 4-slot ring of K-half tiles [256 rows][32 cols] (16KB),
// swizzled: physical granule g holds logical col16 j = g ^ (row&3)  -> bank floor.
// Staged via global_load_lds(16B) with pre-swizzled SOURCE (linear LDS dest).
// 4 phases per K-tile: (k0,mhalf0)(k1,mh0)(k0,mh1)(k1,mh1); stages of tile t+1
// issued at phases 0,1; counted vmcnt(8) keeps 2 half-stages in flight.
template <int BIAS_MODE>
__global__ __launch_bounds__(512, 2) void gemm256(
    const u16* __restrict__ Ag, int lda, long sA,
    const u16* __restrict__ Bg, int ldb, long sB,
    u16* __restrict__ Cg, int ldc, long sC,
    const float* __restrict__ bias, float alpha, int K) {
  __shared__ u16 As[4][8192];
  __shared__ u16 Bs[4][8192];
  const int bz = blockIdx.z;
  const u16* A  = Ag + (size_t)bz * sA;
  const u16* Bm = Bg + (size_t)bz * sB;
  u16* Cb = Cg + (size_t)bz * sC;
  const int bm = blockIdx.y * 256, bn = blockIdx.x * 256;
  const int tid = threadIdx.x;
  const int wid = tid >> 6, lane = tid & 63;
  const int wm = (wid >> 2) * 128, wn = (wid & 3) * 64;
  const int lr = lane & 15, lh = lane >> 4;

  // staging source (pre-swizzled): thread covers (row = l*128 + tid>>2, granule tid&3)
  const int srow = tid >> 2;
  const int sj   = (tid & 3) ^ (srow & 3);
  const u16* Asrc = A  + (size_t)(bm + srow) * lda + sj * 8;
  const u16* Bsrc = Bm + (size_t)(bn + srow) * ldb + sj * 8;

  // LDS read bases (u16 index within slot); frag (r=.. row, col16 = lh) -> g = lh^(r&3)
  const int agx  = ((lh ^ (lr & 3)) << 3);
  const int abase = (wm + lr) * 32 + agx;
  const int bbase = (wn + lr) * 32 + agx;

  f32x4 acc[8][4];
  const f32x4 zero = {0.f, 0.f, 0.f, 0.f};
#pragma unroll
  for (int i = 0; i < 8; ++i)
#pragma unroll
    for (int j = 0; j < 4; ++j) acc[i][j] = zero;

#define STAGE(T, KS) do {                                                   \
    const int _sl = (2 * (T) + (KS)) & 3;                                   \
    const size_t _ko = (size_t)(T) * 64 + (KS) * 32;                        \
    g2lds16(Asrc + _ko, &As[_sl][wid * 512]);                               \
    g2lds16(Bsrc + _ko, &Bs[_sl][wid * 512]);                               \
    g2lds16(Asrc + (size_t)128 * lda + _ko, &As[_sl][4096 + wid * 512]);    \
    g2lds16(Bsrc + (size_t)128 * ldb + _ko, &Bs[_sl][4096 + wid * 512]);    \
  } while (0)

#define COMP(SLOT, MH) do {                                                 \
    const u16* as_ = &As[(SLOT)][abase];                                    \
    const u16* bs_ = &Bs[(SLOT)][bbase];                                    \
    bf16x8 af[4], bfr[4];                                                   \
    _Pragma("unroll") for (int i = 0; i < 4; ++i)                           \
      af[i] = *(const bf16x8*)&as_[((MH) * 4 + i) * 512];                   \
    _Pragma("unroll") for (int i = 0; i < 4; ++i)                           \
      bfr[i] = *(const bf16x8*)&bs_[i * 512];                               \
    __builtin_amdgcn_s_setprio(1);                                          \
    _Pragma("unroll") for (int mi = 0; mi < 4; ++mi)                        \
    _Pragma("unroll") for (int ni = 0; ni < 4; ++ni)                        \
      acc[(MH) * 4 + mi][ni] = __builtin_amdgcn_mfma_f32_16x16x32_bf16(     \
          af[mi], bfr[ni], acc[(MH) * 4 + mi][ni], 0, 0, 0);                \
    __builtin_amdgcn_s_setprio(0);                                          \
  } while (0)

  const int nt = K >> 6;
  STAGE(0, 0);
  STAGE(0, 1);
  for (int t = 0; t < nt; ++t) {
    const int s0 = (2 * t) & 3, s1 = (2 * t + 1) & 3;
    if (t + 1 < nt) { STAGE(t + 1, 0); WAITV8; } else { WAITV4; }
    BAR(); SCHED0();
    COMP(s0, 0);
    if (t + 1 < nt) { STAGE(t + 1, 1); WAITV8; } else { WAITV0; }
    BAR(); SCHED0();
    COMP(s1, 0);
    BAR(); SCHED0();
    COMP(s0, 1);
    BAR(); SCHED0();
    COMP(s1, 1);
  }
#undef STAGE
#undef COMP

#pragma unroll
  for (int mf = 0; mf < 8; ++mf) {
    const int row0 = bm + wm + mf * 16 + lh * 4;
#pragma unroll
    for (int nf = 0; nf < 4; ++nf) {
      const int col = bn + wn + nf * 16 + lr;
      const float ba = (BIAS_MODE == 1) ? bias[col] : 0.f;
#pragma unroll
      for (int r = 0; r < 4; ++r)
        Cb[(size_t)(row0 + r) * ldc + col] = f2bf(acc[mf][nf][r] * alpha + ba);
    }
  }
}

// ---------------- old 128x128 GEMM (kept for V and out-proj) ----------------
#define GBM 128
#define GBN 128
#define GBK 64

template <int BIAS_MODE, int OUT_MODE>
__global__ __launch_bounds__(256) void gemm_abT(
    const u16* __restrict__ Ag, int lda, long sA,
    const u16* __restrict__ Bg, int ldb, long sB,
    void* __restrict__ Cg, int ldc, long sC,
    const float* __restrict__ bias, float alpha,
    const float* __restrict__ xres, int K) {
  __shared__ u16 As[GBM * GBK];
  __shared__ u16 Bs[GBN * GBK];
  const int bz = blockIdx.z;
  const u16* A    = Ag + (size_t)bz * sA;
  const u16* Bmat = Bg + (size_t)bz * sB;
  const int bm = blockIdx.y * GBM, bn = blockIdx.x * GBN;
  const int tid = threadIdx.x;
  const int wid = tid >> 6, lane = tid & 63;
  const int wm = (wid >> 1) * 64, wn = (wid & 1) * 64;
  const int lr = lane & 15, lh = lane >> 4;
  const int srow = lane >> 3, scol = (lane & 7) * 8;

  f32x4 acc[4][4];
  const f32x4 zero = {0.f, 0.f, 0.f, 0.f};
#pragma unroll
  for (int i = 0; i < 4; ++i)
#pragma unroll
    for (int j = 0; j < 4; ++j) acc[i][j] = zero;

  for (int k0 = 0; k0 < K; k0 += GBK) {
    __syncthreads();
#pragma unroll
    for (int i = 0; i < 4; ++i) {
      const int chunk = wid * 4 + i;
      const int row   = chunk * 8 + srow;
      g2lds16(A    + (size_t)(bm + row) * lda + (k0 + scol), &As[chunk * 512]);
      g2lds16(Bmat + (size_t)(bn + row) * ldb + (k0 + scol), &Bs[chunk * 512]);
    }
    __syncthreads();
#pragma unroll
    for (int ks = 0; ks < 2; ++ks) {
      bf16x8 a_[4], b_[4];
#pragma unroll
      for (int m = 0; m < 4; ++m)
        a_[m] = *(const bf16x8*)&As[(wm + m * 16 + lr) * GBK + ks * 32 + lh * 8];
#pragma unroll
      for (int n = 0; n < 4; ++n)
        b_[n] = *(const bf16x8*)&Bs[(wn + n * 16 + lr) * GBK + ks * 32 + lh * 8];
#pragma unroll
      for (int m = 0; m < 4; ++m)
#pragma unroll
        for (int n = 0; n < 4; ++n)
          acc[m][n] = __builtin_amdgcn_mfma_f32_16x16x32_bf16(a_[m], b_[n], acc[m][n], 0, 0, 0);
    }
  }

  if (OUT_MODE == 0) {
    u16* Cb = (u16*)Cg + (size_t)bz * sC;
#pragma unroll
    for (int m = 0; m < 4; ++m) {
      const int row0 = bm + wm + m * 16 + lh * 4;
#pragma unroll
      for (int n = 0; n < 4; ++n) {
        const int col = bn + wn + n * 16 + lr;
        float bn_ = (BIAS_MODE == 1) ? bias[col] : 0.f;
#pragma unroll
        for (int r = 0; r < 4; ++r) {
          float bb = (BIAS_MODE == 2) ? bias[row0 + r] : bn_;
          Cb[(size_t)(row0 + r) * ldc + col] = f2bf(acc[m][n][r] * alpha + bb);
        }
      }
    }
  } else {
    float* Ob = (float*)Cg;
#pragma unroll
    for (int m = 0; m < 4; ++m) {
      const int row0 = bm + wm + m * 16 + lh * 4;
#pragma unroll
      for (int n = 0; n < 4; ++n) {
        const int col = bn + wn + n * 16 + lr;
        const int bb = col >> 12, sp = col & (S_ - 1);
#pragma unroll
        for (int r = 0; r < 4; ++r) {
          const int o = row0 + r;
          const size_t idx = ((size_t)bb * C_ + o) * S_ + sp;
          Ob[idx] = acc[m][n][r] * alpha + bias[o] + xres[idx];
        }
      }
    }
  }
}

// ---------------- row softmax, in place on bf16 scores ----------------
__global__ __launch_bounds__(256) void softmax_rows(u16* __restrict__ sc) {
  const size_t base = ((size_t)blockIdx.y * S_ + blockIdx.x) * S_;
  uint4* r4 = (uint4*)(sc + base);
  const int tid = threadIdx.x;
  uint4 u0 = r4[tid], u1 = r4[tid + 256];
  float f[16];
  {
    const unsigned* pu = (const unsigned*)&u0;
    const unsigned* pv = (const unsigned*)&u1;
#pragma unroll
    for (int i = 0; i < 4; ++i) {
      f[2 * i]     = bf2f((u16)(pu[i] & 0xffffu));
      f[2 * i + 1] = bf2f((u16)(pu[i] >> 16));
      f[8 + 2 * i]     = bf2f((u16)(pv[i] & 0xffffu));
      f[8 + 2 * i + 1] = bf2f((u16)(pv[i] >> 16));
    }
  }
  float mx = f[0];
#pragma unroll
  for (int i = 1; i < 16; ++i) mx = fmaxf(mx, f[i]);
#pragma unroll
  for (int o = 32; o; o >>= 1) mx = fmaxf(mx, __shfl_xor(mx, o, 64));
  __shared__ float red[8];
  const int wid = tid >> 6, lane = tid & 63;
  if (lane == 0) red[wid] = mx;
  __syncthreads();
  mx = fmaxf(fmaxf(red[0], red[1]), fmaxf(red[2], red[3]));
  float s = 0.f;
#pragma unroll
  for (int i = 0; i < 16; ++i) { f[i] = __expf(f[i] - mx); s += f[i]; }
#pragma unroll
  for (int o = 32; o; o >>= 1) s += __shfl_xor(s, o, 64);
  if (lane == 0) red[4 + wid] = s;
  __syncthreads();
  s = red[4] + red[5] + red[6] + red[7];
  const float inv = 1.f / s;
  unsigned o0[4], o1[4];
#pragma unroll
  for (int i = 0; i < 4; ++i) {
    o0[i] = (unsigned)f2bf(f[2 * i] * inv)     | ((unsigned)f2bf(f[2 * i + 1] * inv) << 16);
    o1[i] = (unsigned)f2bf(f[8 + 2 * i] * inv) | ((unsigned)f2bf(f[8 + 2 * i + 1] * inv) << 16);
  }
  r4[tid]       = *(uint4*)o0;
  r4[tid + 256] = *(uint4*)o1;
}

extern "C" void kernel_launch(void* const* d_in, const int* in_sizes, int n_in,
                              void* d_out, int out_size, void* d_ws, size_t ws_size,
                              hipStream_t stream) {
  const float* x     = (const float*)d_in[0];
  const float* gamma = (const float*)d_in[1];
  const float* beta  = (const float*)d_in[2];
  const float* wq = (const float*)d_in[3];
  const float* bq = (const float*)d_in[4];
  const float* wk = (const float*)d_in[5];
  const float* bk = (const float*)d_in[6];
  const float* wv = (const float*)d_in[7];
  const float* bv = (const float*)d_in[8];
  const float* wo = (const float*)d_in[9];
  const float* bo = (const float*)d_in[10];
  float* out = (float*)d_out;

  // ws: stats 1KB | wq,wk,wv,wo bf16 (4x512KB) | bqk 4KB | ht 16MB | qkt 32MB | vv 16MB | sc 128MB
  char* ws = (char*)d_ws;
  float* stats = (float*)ws;
  u16* wqb = (u16*)(ws + 1024);
  u16* wkb = wqb + 262144;   // contiguous after wqb -> [wq;wk] is one 1024x512 matrix
  u16* wvb = wkb + 262144;
  u16* wob = wvb + 262144;
  float* bqk = (float*)(wob + 262144);
  u16* ht  = (u16*)((char*)bqk + 4096);  // [B*S, C]
  u16* qkt = ht + 8388608;               // [B*S, 1024]  (q | k)
  u16* vv  = qkt + 16777216;             // [C, B*S]
  u16* sc  = vv + 8388608;               // [B, S, S]
  u16* ha  = qkt;                        // hattnT reuses qkt (dead after scores)

  f32_to_bf16<<<1024, 256, 0, stream>>>(wq, wqb, 262144);
  f32_to_bf16<<<1024, 256, 0, stream>>>(wk, wkb, 262144);
  f32_to_bf16<<<1024, 256, 0, stream>>>(wv, wvb, 262144);
  f32_to_bf16<<<1024, 256, 0, stream>>>(wo, wob, 262144);
  concat_bias<<<4, 256, 0, stream>>>(bq, bk, bqk);

  gn_stats<<<128, 256, 0, stream>>>(x, stats);
  gn_apply_t<<<dim3(128, 16, 4), dim3(32, 8), 0, stream>>>(x, gamma, beta, stats, ht);

  // fused Q|K projection: qkt[bs, 0:512]=Q, [512:1024]=K
  gemm256<1><<<dim3(4, 64, 1), 512, 0, stream>>>(ht, 512, 0, wqb, 512, 0,
                                                 qkt, 1024, 0, bqk, 1.f, 512);
  // V[c, b*S+s] (old kernel)
  gemm_abT<2, 0><<<dim3(128, 4, 1), 256, 0, stream>>>(wvb, 512, 0, ht, 512, 0,
                                                      vv, 16384, 0, bv, 1.f, nullptr, 512);
  // scores[b,i,j] = scale * Q_b[i,:].K_b[j,:]
  gemm256<0><<<dim3(16, 16, 4), 512, 0, stream>>>(qkt, 1024, 4194304, qkt + 512, 1024, 4194304,
                                                  sc, 4096, 16777216, nullptr,
                                                  0.04419417382415922f, 512);
  softmax_rows<<<dim3(4096, 4), 256, 0, stream>>>(sc);
  // hattnT[b*S+i, c] = sum_j P_b[i,j] * V_b[c,j]
  gemm256<0><<<dim3(2, 16, 4), 512, 0, stream>>>(sc, 4096, 16777216, vv, 16384, 4096,
                                                 ha, 512, 2097152, nullptr, 1.f, 4096);
  // out[b,o,s] = Wo@hattn + bo + x  (old kernel, fused residual epilogue)
  gemm_abT<2, 1><<<dim3(128, 4, 1), 256, 0, stream>>>(wob, 512, 0, ha, 512, 0,
                                                      out, 0, 0, bo, 1.f, x, 512);
}

// Round 3
// 323.724 us; speedup vs baseline: 1.2369x; 1.2369x over previous
//
#include <hip/hip_runtime.h>

#define B_   4
#define C_   512
#define S_   4096
#define G_   32
#define CPG_ 16
#define EPS_ 1e-6f

typedef unsigned short u16;
typedef __bf16 bf16x8 __attribute__((ext_vector_type(8)));
typedef float  f32x4  __attribute__((ext_vector_type(4)));

__device__ __forceinline__ u16 f2bf(float f) {
  unsigned u = __float_as_uint(f);
  u += 0x7fffu + ((u >> 16) & 1u);   // RNE
  return (u16)(u >> 16);
}
__device__ __forceinline__ float bf2f(u16 h) {
  return __uint_as_float((unsigned)h << 16);
}

__device__ __forceinline__ void g2lds16(const void* g, void* l) {
  __builtin_amdgcn_global_load_lds(
      (const __attribute__((address_space(1))) void*)g,
      (__attribute__((address_space(3))) void*)l, 16, 0, 0);
}

#define BAR()    __builtin_amdgcn_s_barrier()
#define SCHED0() __builtin_amdgcn_sched_barrier(0)
#define WAITV4   asm volatile("s_waitcnt vmcnt(4)" ::: "memory")
#define WAITV3   asm volatile("s_waitcnt vmcnt(3)" ::: "memory")
#define WAITV0   asm volatile("s_waitcnt vmcnt(0)" ::: "memory")

// chunked XCD swizzle: consecutive original flat ids land on ONE XCD (m204 bijective,
// requires nwg % 8 == 0 — all grids here satisfy it)
__device__ __forceinline__ void xcd_swz(int& bx, int& by, int& bz) {
  const int gx = gridDim.x, gy = gridDim.y;
  const int nwg = gx * gy * (int)gridDim.z;
  const int flat = blockIdx.x + gx * (blockIdx.y + gy * blockIdx.z);
  const int q = nwg >> 3;
  const int nf = (flat & 7) * q + (flat >> 3);
  bx = nf % gx;
  const int r = nf / gx;
  by = r % gy;
  bz = r / gy;
}

// ---------------- fp32 -> bf16 weight conversion ----------------
__global__ __launch_bounds__(256) void f32_to_bf16(const float* __restrict__ in,
                                                   u16* __restrict__ out, int n) {
  int i = blockIdx.x * 256 + threadIdx.x;
  if (i < n) out[i] = f2bf(in[i]);
}

__global__ __launch_bounds__(256) void concat_bias(const float* __restrict__ a,
                                                   const float* __restrict__ b,
                                                   float* __restrict__ o) {
  int i = blockIdx.x * 256 + threadIdx.x;  // grid 4 -> 1024
  o[i] = (i < 512) ? a[i] : b[i - 512];
}

// ---------------- GroupNorm stats: one block per (b,g) ----------------
__global__ __launch_bounds__(256) void gn_stats(const float* __restrict__ x,
                                                float* __restrict__ stats) {
  const int bg = blockIdx.x;
  const float4* p4 = (const float4*)(x + (size_t)bg * (CPG_ * S_));
  float s = 0.f, ss = 0.f;
  const int tid = threadIdx.x;
  for (int i = tid; i < CPG_ * S_ / 4; i += 256) {
    float4 v = p4[i];
    s  += v.x + v.y + v.z + v.w;
    ss += v.x * v.x + v.y * v.y + v.z * v.z + v.w * v.w;
  }
#pragma unroll
  for (int o = 32; o; o >>= 1) { s += __shfl_xor(s, o, 64); ss += __shfl_xor(ss, o, 64); }
  __shared__ float sm[8];
  const int wid = tid >> 6, lane = tid & 63;
  if (lane == 0) { sm[wid * 2] = s; sm[wid * 2 + 1] = ss; }
  __syncthreads();
  if (tid == 0) {
    s  = sm[0] + sm[2] + sm[4] + sm[6];
    ss = sm[1] + sm[3] + sm[5] + sm[7];
    const float inv = 1.f / (float)(CPG_ * S_);
    float mu = s * inv;
    float var = ss * inv - mu * mu;
    stats[bg * 2]     = mu;
    stats[bg * 2 + 1] = rsqrtf(var + EPS_);
  }
}

// ---------------- normalize + transpose: x[b,c,s] -> ht[b*s, c] bf16 ----------------
__global__ __launch_bounds__(256) void gn_apply_t(const float* __restrict__ x,
                                                  const float* __restrict__ gamma,
                                                  const float* __restrict__ beta,
                                                  const float* __restrict__ stats,
                                                  u16* __restrict__ ht) {
  __shared__ float tile[32][33];
  const int b = blockIdx.z, c0 = blockIdx.y * 32, s0 = blockIdx.x * 32;
  const int tx = threadIdx.x, ty = threadIdx.y;
#pragma unroll
  for (int i = 0; i < 4; ++i) {
    const int c  = c0 + ty + i * 8;
    const float mu = stats[(b * G_ + (c >> 4)) * 2];
    const float rs = stats[(b * G_ + (c >> 4)) * 2 + 1];
    const float v  = x[((size_t)b * C_ + c) * S_ + s0 + tx];
    tile[ty + i * 8][tx] = (v - mu) * rs * gamma[c] + beta[c];
  }
  __syncthreads();
#pragma unroll
  for (int i = 0; i < 4; ++i) {
    const int s = s0 + ty + i * 8;
    ht[((size_t)b * S_ + s) * C_ + c0 + tx] = f2bf(tile[tx][ty + i * 8]);
  }
}

// ================= 256x256 phase-split GEMM (T1+T2+T3+T4+T5) =================
// C[m,n] = alpha * sum_k A[m,k]*B[n,k] (+bias[n]); A,B bf16 K-contiguous.
// 512 thr = 8 waves (2m x 4n), per-wave 128x64 (8x4 frags of 16x16x32).
// LDS: 4-slot K-half ring per operand, slot = [256 rows][32 u16], swizzled:
// phys granule p = g ^ ((row>>1)&3)  -> 2-way (free) bank pattern on ds_read_b128.
// 4 phases/K-tile: (kh0,mh0)(kh0,mh1)(kh1,mh0)(kh1,mh1); B-frags read once per kh,
// held in regs across mh phases. One stage-quarter (2 gloads) issued per phase;
// counted vmcnt(4) at phases 0/2 drains loads issued one full K-tile earlier.
#define STAGE_A(T, KS) do {                                                  \
    const int _sl = (2 * (T) + (KS)) & 3;                                    \
    const size_t _ko = (size_t)(T) * 64 + (KS) * 32;                         \
    g2lds16(Asrc + _ko,  &As[_sl][wid * 512]);                               \
    g2lds16(Asrc2 + _ko, &As[_sl][4096 + wid * 512]);                        \
  } while (0)
#define STAGE_B(T, KS) do {                                                  \
    const int _sl = (2 * (T) + (KS)) & 3;                                    \
    const size_t _ko = (size_t)(T) * 64 + (KS) * 32;                         \
    g2lds16(Bsrc + _ko,  &Bs[_sl][wid * 512]);                               \
    g2lds16(Bsrc2 + _ko, &Bs[_sl][4096 + wid * 512]);                        \
  } while (0)
#define LDB4(SL)                                                             \
  _Pragma("unroll") for (int i = 0; i < 4; ++i)                              \
      bfr[i] = *(const bf16x8*)&Bs[(SL)][bbase + i * 512];
#define LDA4(SL, MH)                                                         \
  _Pragma("unroll") for (int i = 0; i < 4; ++i)                              \
      af[i] = *(const bf16x8*)&As[(SL)][abase + ((MH) * 4 + i) * 512];
#define MFMA16(MH) do {                                                      \
    __builtin_amdgcn_s_setprio(1);                                           \
    _Pragma("unroll") for (int mi = 0; mi < 4; ++mi)                         \
    _Pragma("unroll") for (int ni = 0; ni < 4; ++ni)                         \
      acc[(MH) * 4 + mi][ni] = __builtin_amdgcn_mfma_f32_16x16x32_bf16(      \
          af[mi], bfr[ni], acc[(MH) * 4 + mi][ni], 0, 0, 0);                 \
    __builtin_amdgcn_s_setprio(0);                                           \
  } while (0)

template <int BIAS_MODE>
__global__ __launch_bounds__(512, 2) void gemm256(
    const u16* __restrict__ Ag, int lda, long sA,
    const u16* __restrict__ Bg, int ldb, long sB,
    u16* __restrict__ Cg, int ldc, long sC,
    const float* __restrict__ bias, float alpha, int K) {
  __shared__ u16 As[4][8192];
  __shared__ u16 Bs[4][8192];
  int bx, by, bz;
  xcd_swz(bx, by, bz);
  const u16* A  = Ag + (size_t)bz * sA;
  const u16* Bm = Bg + (size_t)bz * sB;
  u16* Cb = Cg + (size_t)bz * sC;
  const int bm = by * 256, bn = bx * 256;
  const int tid = threadIdx.x;
  const int wid = tid >> 6, lane = tid & 63;
  const int wm = (wid >> 2) * 128, wn = (wid & 3) * 64;
  const int lr = lane & 15, lh = lane >> 4;

  // staging: lane covers (row = wid*16 + lane>>2 [+128], phys granule lane&3)
  const int srow = wid * 16 + (lane >> 2);
  const int sg   = (lane & 3) ^ ((srow >> 1) & 3);
  const u16* Asrc  = A  + (size_t)(bm + srow) * lda + sg * 8;
  const u16* Asrc2 = Asrc + (size_t)128 * lda;
  const u16* Bsrc  = Bm + (size_t)(bn + srow) * ldb + sg * 8;
  const u16* Bsrc2 = Bsrc + (size_t)128 * ldb;

  const int swz   = (lh ^ ((lr >> 1) & 3)) << 3;
  const int abase = (wm + lr) * 32 + swz;
  const int bbase = (wn + lr) * 32 + swz;

  // preload bias BEFORE staging so the vmcnt ledger stays exact (4 oldest loads
  // drain at the first WAITV4 together with the kh0 stages)
  float bias_v[4] = {0.f, 0.f, 0.f, 0.f};
  if (BIAS_MODE == 1) {
#pragma unroll
    for (int nf = 0; nf < 4; ++nf) bias_v[nf] = bias[bn + wn + nf * 16 + lr];
  }
  SCHED0();

  f32x4 acc[8][4];
  const f32x4 zero = {0.f, 0.f, 0.f, 0.f};
#pragma unroll
  for (int i = 0; i < 8; ++i)
#pragma unroll
    for (int j = 0; j < 4; ++j) acc[i][j] = zero;

  STAGE_A(0, 0); STAGE_B(0, 0); STAGE_A(0, 1); STAGE_B(0, 1);

  const int nt = K >> 6;
  for (int t = 0; t < nt; ++t) {
    const int s0 = (2 * t) & 3, s1 = s0 + 1;
    const bool pre = (t + 1 < nt);
    bf16x8 bfr[4], af[4];
    // ---- P0 (kh0, mh0): drain t's kh0 stages
    WAITV4;
    BAR(); SCHED0();
    LDB4(s0);
    LDA4(s0, 0);
    if (pre) STAGE_A(t + 1, 0);
    MFMA16(0);
    // ---- P1 (kh0, mh1): reuse bfr
    BAR(); SCHED0();
    LDA4(s0, 1);
    if (pre) STAGE_B(t + 1, 0);
    MFMA16(1);
    // ---- P2 (kh1, mh0): drain t's kh1 stages
    if (pre) { WAITV4; } else { WAITV0; }
    BAR(); SCHED0();
    LDB4(s1);
    LDA4(s1, 0);
    if (pre) STAGE_A(t + 1, 1);
    MFMA16(0);
    // ---- P3 (kh1, mh1)
    BAR(); SCHED0();
    LDA4(s1, 1);
    if (pre) STAGE_B(t + 1, 1);
    MFMA16(1);
  }
  SCHED0();

#pragma unroll
  for (int mf = 0; mf < 8; ++mf) {
    const int row0 = bm + wm + mf * 16 + lh * 4;
#pragma unroll
    for (int nf = 0; nf < 4; ++nf) {
      const int col = bn + wn + nf * 16 + lr;
#pragma unroll
      for (int r = 0; r < 4; ++r)
        Cb[(size_t)(row0 + r) * ldc + col] = f2bf(acc[mf][nf][r] * alpha + bias_v[nf]);
    }
  }
}

// ============ 256x128 phase-split GEMM for PV (full-GPU grid) ============
// 512 thr = 8 waves (4m x 2n), per-wave 64x64 (4x4 frags). 2 phases/K-tile.
// A: 4-slot ring [256][32]; B: 4-slot ring [128][32]; same swizzle.
// Stages per phase: A-half (2 loads) + B-half (1 load); vmcnt(3) per phase.
__global__ __launch_bounds__(512, 2) void gemm256pv(
    const u16* __restrict__ Ag, int lda, long sA,
    const u16* __restrict__ Bg, int ldb, long sB,
    u16* __restrict__ Cg, int ldc, long sC, int K) {
  __shared__ u16 As[4][8192];
  __shared__ u16 Bs[4][4096];
  int bx, by, bz;
  xcd_swz(bx, by, bz);
  const u16* A  = Ag + (size_t)bz * sA;
  const u16* Bm = Bg + (size_t)bz * sB;
  u16* Cb = Cg + (size_t)bz * sC;
  const int bm = by * 256, bn = bx * 128;
  const int tid = threadIdx.x;
  const int wid = tid >> 6, lane = tid & 63;
  const int wm = (wid >> 1) * 64, wn = (wid & 1) * 64;
  const int lr = lane & 15, lh = lane >> 4;

  const int srow = wid * 16 + (lane >> 2);
  const int sg   = (lane & 3) ^ ((srow >> 1) & 3);
  const u16* Asrc  = A  + (size_t)(bm + srow) * lda + sg * 8;
  const u16* Asrc2 = Asrc + (size_t)128 * lda;
  const u16* Bsrc  = Bm + (size_t)(bn + srow) * ldb + sg * 8;

  const int swz   = (lh ^ ((lr >> 1) & 3)) << 3;
  const int abase = (wm + lr) * 32 + swz;
  const int bbase = (wn + lr) * 32 + swz;

#define PSTAGE_A(T, KS) do {                                                 \
    const int _sl = (2 * (T) + (KS)) & 3;                                    \
    const size_t _ko = (size_t)(T) * 64 + (KS) * 32;                         \
    g2lds16(Asrc + _ko,  &As[_sl][wid * 512]);                               \
    g2lds16(Asrc2 + _ko, &As[_sl][4096 + wid * 512]);                        \
  } while (0)
#define PSTAGE_B(T, KS) do {                                                 \
    const int _sl = (2 * (T) + (KS)) & 3;                                    \
    const size_t _ko = (size_t)(T) * 64 + (KS) * 32;                         \
    g2lds16(Bsrc + _ko, &Bs[_sl][wid * 512]);                                \
  } while (0)

  f32x4 acc[4][4];
  const f32x4 zero = {0.f, 0.f, 0.f, 0.f};
#pragma unroll
  for (int i = 0; i < 4; ++i)
#pragma unroll
    for (int j = 0; j < 4; ++j) acc[i][j] = zero;

  PSTAGE_A(0, 0); PSTAGE_B(0, 0); PSTAGE_A(0, 1); PSTAGE_B(0, 1);

  const int nt = K >> 6;
  for (int t = 0; t < nt; ++t) {
    const int s0 = (2 * t) & 3, s1 = s0 + 1;
    const bool pre = (t + 1 < nt);
    bf16x8 bfr[4], af[4];
    // ---- P0 (kh0)
    WAITV3;
    BAR(); SCHED0();
    _Pragma("unroll") for (int i = 0; i < 4; ++i)
        bfr[i] = *(const bf16x8*)&Bs[s0][bbase + i * 512];
    _Pragma("unroll") for (int i = 0; i < 4; ++i)
        af[i] = *(const bf16x8*)&As[s0][abase + i * 512];
    if (pre) { PSTAGE_A(t + 1, 0); PSTAGE_B(t + 1, 0); }
    __builtin_amdgcn_s_setprio(1);
#pragma unroll
    for (int mi = 0; mi < 4; ++mi)
#pragma unroll
      for (int ni = 0; ni < 4; ++ni)
        acc[mi][ni] = __builtin_amdgcn_mfma_f32_16x16x32_bf16(af[mi], bfr[ni], acc[mi][ni], 0, 0, 0);
    __builtin_amdgcn_s_setprio(0);
    // ---- P1 (kh1)
    if (pre) { WAITV3; } else { WAITV0; }
    BAR(); SCHED0();
    _Pragma("unroll") for (int i = 0; i < 4; ++i)
        bfr[i] = *(const bf16x8*)&Bs[s1][bbase + i * 512];
    _Pragma("unroll") for (int i = 0; i < 4; ++i)
        af[i] = *(const bf16x8*)&As[s1][abase + i * 512];
    if (pre) { PSTAGE_A(t + 1, 1); PSTAGE_B(t + 1, 1); }
    __builtin_amdgcn_s_setprio(1);
#pragma unroll
    for (int mi = 0; mi < 4; ++mi)
#pragma unroll
      for (int ni = 0; ni < 4; ++ni)
        acc[mi][ni] = __builtin_amdgcn_mfma_f32_16x16x32_bf16(af[mi], bfr[ni], acc[mi][ni], 0, 0, 0);
    __builtin_amdgcn_s_setprio(0);
  }
  SCHED0();

#pragma unroll
  for (int mf = 0; mf < 4; ++mf) {
    const int row0 = bm + wm + mf * 16 + lh * 4;
#pragma unroll
    for (int nf = 0; nf < 4; ++nf) {
      const int col = bn + wn + nf * 16 + lr;
#pragma unroll
      for (int r = 0; r < 4; ++r)
        Cb[(size_t)(row0 + r) * ldc + col] = f2bf(acc[mf][nf][r]);
    }
  }
}

// ---------------- old 128x128 GEMM (kept for V and out-proj) ----------------
#define GBM 128
#define GBN 128
#define GBK 64

template <int BIAS_MODE, int OUT_MODE>
__global__ __launch_bounds__(256) void gemm_abT(
    const u16* __restrict__ Ag, int lda, long sA,
    const u16* __restrict__ Bg, int ldb, long sB,
    void* __restrict__ Cg, int ldc, long sC,
    const float* __restrict__ bias, float alpha,
    const float* __restrict__ xres, int K) {
  __shared__ u16 As[GBM * GBK];
  __shared__ u16 Bs[GBN * GBK];
  const int bz = blockIdx.z;
  const u16* A    = Ag + (size_t)bz * sA;
  const u16* Bmat = Bg + (size_t)bz * sB;
  const int bm = blockIdx.y * GBM, bn = blockIdx.x * GBN;
  const int tid = threadIdx.x;
  const int wid = tid >> 6, lane = tid & 63;
  const int wm = (wid >> 1) * 64, wn = (wid & 1) * 64;
  const int lr = lane & 15, lh = lane >> 4;
  const int srow = lane >> 3, scol = (lane & 7) * 8;

  f32x4 acc[4][4];
  const f32x4 zero = {0.f, 0.f, 0.f, 0.f};
#pragma unroll
  for (int i = 0; i < 4; ++i)
#pragma unroll
    for (int j = 0; j < 4; ++j) acc[i][j] = zero;

  for (int k0 = 0; k0 < K; k0 += GBK) {
    __syncthreads();
#pragma unroll
    for (int i = 0; i < 4; ++i) {
      const int chunk = wid * 4 + i;
      const int row   = chunk * 8 + srow;
      g2lds16(A    + (size_t)(bm + row) * lda + (k0 + scol), &As[chunk * 512]);
      g2lds16(Bmat + (size_t)(bn + row) * ldb + (k0 + scol), &Bs[chunk * 512]);
    }
    __syncthreads();
#pragma unroll
    for (int ks = 0; ks < 2; ++ks) {
      bf16x8 a_[4], b_[4];
#pragma unroll
      for (int m = 0; m < 4; ++m)
        a_[m] = *(const bf16x8*)&As[(wm + m * 16 + lr) * GBK + ks * 32 + lh * 8];
#pragma unroll
      for (int n = 0; n < 4; ++n)
        b_[n] = *(const bf16x8*)&Bs[(wn + n * 16 + lr) * GBK + ks * 32 + lh * 8];
#pragma unroll
      for (int m = 0; m < 4; ++m)
#pragma unroll
        for (int n = 0; n < 4; ++n)
          acc[m][n] = __builtin_amdgcn_mfma_f32_16x16x32_bf16(a_[m], b_[n], acc[m][n], 0, 0, 0);
    }
  }

  if (OUT_MODE == 0) {
    u16* Cb = (u16*)Cg + (size_t)bz * sC;
#pragma unroll
    for (int m = 0; m < 4; ++m) {
      const int row0 = bm + wm + m * 16 + lh * 4;
#pragma unroll
      for (int n = 0; n < 4; ++n) {
        const int col = bn + wn + n * 16 + lr;
        float bn_ = (BIAS_MODE == 1) ? bias[col] : 0.f;
#pragma unroll
        for (int r = 0; r < 4; ++r) {
          float bb = (BIAS_MODE == 2) ? bias[row0 + r] : bn_;
          Cb[(size_t)(row0 + r) * ldc + col] = f2bf(acc[m][n][r] * alpha + bb);
        }
      }
    }
  } else {
    float* Ob = (float*)Cg;
#pragma unroll
    for (int m = 0; m < 4; ++m) {
      const int row0 = bm + wm + m * 16 + lh * 4;
#pragma unroll
      for (int n = 0; n < 4; ++n) {
        const int col = bn + wn + n * 16 + lr;
        const int bb = col >> 12, sp = col & (S_ - 1);
#pragma unroll
        for (int r = 0; r < 4; ++r) {
          const int o = row0 + r;
          const size_t idx = ((size_t)bb * C_ + o) * S_ + sp;
          Ob[idx] = acc[m][n][r] * alpha + bias[o] + xres[idx];
        }
      }
    }
  }
}

// ---------------- row softmax, in place on bf16 scores ----------------
__global__ __launch_bounds__(256) void softmax_rows(u16* __restrict__ sc) {
  const size_t base = ((size_t)blockIdx.y * S_ + blockIdx.x) * S_;
  uint4* r4 = (uint4*)(sc + base);
  const int tid = threadIdx.x;
  uint4 u0 = r4[tid], u1 = r4[tid + 256];
  float f[16];
  {
    const unsigned* pu = (const unsigned*)&u0;
    const unsigned* pv = (const unsigned*)&u1;
#pragma unroll
    for (int i = 0; i < 4; ++i) {
      f[2 * i]     = bf2f((u16)(pu[i] & 0xffffu));
      f[2 * i + 1] = bf2f((u16)(pu[i] >> 16));
      f[8 + 2 * i]     = bf2f((u16)(pv[i] & 0xffffu));
      f[8 + 2 * i + 1] = bf2f((u16)(pv[i] >> 16));
    }
  }
  float mx = f[0];
#pragma unroll
  for (int i = 1; i < 16; ++i) mx = fmaxf(mx, f[i]);
#pragma unroll
  for (int o = 32; o; o >>= 1) mx = fmaxf(mx, __shfl_xor(mx, o, 64));
  __shared__ float red[8];
  const int wid = tid >> 6, lane = tid & 63;
  if (lane == 0) red[wid] = mx;
  __syncthreads();
  mx = fmaxf(fmaxf(red[0], red[1]), fmaxf(red[2], red[3]));
  float s = 0.f;
#pragma unroll
  for (int i = 0; i < 16; ++i) { f[i] = __expf(f[i] - mx); s += f[i]; }
#pragma unroll
  for (int o = 32; o; o >>= 1) s += __shfl_xor(s, o, 64);
  if (lane == 0) red[4 + wid] = s;
  __syncthreads();
  s = red[4] + red[5] + red[6] + red[7];
  const float inv = 1.f / s;
  unsigned o0[4], o1[4];
#pragma unroll
  for (int i = 0; i < 4; ++i) {
    o0[i] = (unsigned)f2bf(f[2 * i] * inv)     | ((unsigned)f2bf(f[2 * i + 1] * inv) << 16);
    o1[i] = (unsigned)f2bf(f[8 + 2 * i] * inv) | ((unsigned)f2bf(f[8 + 2 * i + 1] * inv) << 16);
  }
  r4[tid]       = *(uint4*)o0;
  r4[tid + 256] = *(uint4*)o1;
}

extern "C" void kernel_launch(void* const* d_in, const int* in_sizes, int n_in,
                              void* d_out, int out_size, void* d_ws, size_t ws_size,
                              hipStream_t stream) {
  const float* x     = (const float*)d_in[0];
  const float* gamma = (const float*)d_in[1];
  const float* beta  = (const float*)d_in[2];
  const float* wq = (const float*)d_in[3];
  const float* bq = (const float*)d_in[4];
  const float* wk = (const float*)d_in[5];
  const float* bk = (const float*)d_in[6];
  const float* wv = (const float*)d_in[7];
  const float* bv = (const float*)d_in[8];
  const float* wo = (const float*)d_in[9];
  const float* bo = (const float*)d_in[10];
  float* out = (float*)d_out;

  // ws: stats 1KB | wq,wk,wv,wo bf16 (4x512KB) | bqk 4KB | ht 16MB | qkt 32MB | vv 16MB | sc 128MB
  char* ws = (char*)d_ws;
  float* stats = (float*)ws;
  u16* wqb = (u16*)(ws + 1024);
  u16* wkb = wqb + 262144;   // contiguous after wqb -> [wq;wk] is one 1024x512 matrix
  u16* wvb = wkb + 262144;
  u16* wob = wvb + 262144;
  float* bqk = (float*)(wob + 262144);
  u16* ht  = (u16*)((char*)bqk + 4096);  // [B*S, C]
  u16* qkt = ht + 8388608;               // [B*S, 1024]  (q | k)
  u16* vv  = qkt + 16777216;             // [C, B*S]
  u16* sc  = vv + 8388608;               // [B, S, S]
  u16* ha  = qkt;                        // hattnT reuses qkt (dead after scores)

  f32_to_bf16<<<1024, 256, 0, stream>>>(wq, wqb, 262144);
  f32_to_bf16<<<1024, 256, 0, stream>>>(wk, wkb, 262144);
  f32_to_bf16<<<1024, 256, 0, stream>>>(wv, wvb, 262144);
  f32_to_bf16<<<1024, 256, 0, stream>>>(wo, wob, 262144);
  concat_bias<<<4, 256, 0, stream>>>(bq, bk, bqk);

  gn_stats<<<128, 256, 0, stream>>>(x, stats);
  gn_apply_t<<<dim3(128, 16, 4), dim3(32, 8), 0, stream>>>(x, gamma, beta, stats, ht);

  // fused Q|K projection: qkt[bs, 0:512]=Q, [512:1024]=K
  gemm256<1><<<dim3(4, 64, 1), 512, 0, stream>>>(ht, 512, 0, wqb, 512, 0,
                                                 qkt, 1024, 0, bqk, 1.f, 512);
  // V[c, b*S+s] (old kernel)
  gemm_abT<2, 0><<<dim3(128, 4, 1), 256, 0, stream>>>(wvb, 512, 0, ht, 512, 0,
                                                      vv, 16384, 0, bv, 1.f, nullptr, 512);
  // scores[b,i,j] = scale * Q_b[i,:].K_b[j,:]
  gemm256<0><<<dim3(16, 16, 4), 512, 0, stream>>>(qkt, 1024, 4194304, qkt + 512, 1024, 4194304,
                                                  sc, 4096, 16777216, nullptr,
                                                  0.04419417382415922f, 512);
  softmax_rows<<<dim3(4096, 4), 256, 0, stream>>>(sc);
  // hattnT[b*S+i, c] = sum_j P_b[i,j] * V_b[c,j]   (full-GPU 256x128 kernel)
  gemm256pv<<<dim3(4, 16, 4), 512, 0, stream>>>(sc, 4096, 16777216, vv, 16384, 4096,
                                                ha, 512, 2097152, 4096);
  // out[b,o,s] = Wo@hattn + bo + x  (old kernel, fused residual epilogue)
  gemm_abT<2, 1><<<dim3(128, 4, 1), 256, 0, stream>>>(wob, 512, 0, ha, 512, 0,
                                                      out, 0, 0, bo, 1.f, x, 512);
}